// Round 11
// baseline (159.109 us; speedup 1.0000x reference)
//
#include <hip/hip_runtime.h>
#include <hip/hip_bf16.h>

#define BB 4
#define SS 2048
#define EE 512
#define HH 8
#define DD 64

typedef __attribute__((ext_vector_type(8))) short bf16x8;   // 8 bf16 = 4 VGPRs
typedef __attribute__((ext_vector_type(4))) float f32x4;
typedef __attribute__((ext_vector_type(4))) unsigned int u32x4;

__device__ __forceinline__ unsigned short f2bf(float f) {
    __hip_bfloat16 h = __float2bfloat16(f);   // round-to-nearest
    return *reinterpret_cast<unsigned short*>(&h);
}

// HW packed f32->bf16 (RTNE). lo -> low 16, hi -> high 16 (T12 recipe).
__device__ __forceinline__ unsigned int cvtpk(float lo, float hi) {
    unsigned int r;
    asm("v_cvt_pk_bf16_f32 %0, %1, %2" : "=v"(r) : "v"(lo), "v"(hi));
    return r;
}

// Raw v_exp_f32 (2^x). Softmax wants flush-to-zero; |x| <~ 8 here.
__device__ __forceinline__ float ex2(float x) {
    float r;
    asm("v_exp_f32 %0, %1" : "=v"(r) : "v"(x));
    return r;
}

// gfx950 half-wave swaps (T12).
__device__ __forceinline__ void pl32(unsigned int& a, unsigned int& b) {
    asm("v_permlane32_swap_b32 %0, %1" : "+v"(a), "+v"(b));
}
__device__ __forceinline__ void pl16(unsigned int& a, unsigned int& b) {
    asm("v_permlane16_swap_b32 %0, %1" : "+v"(a), "+v"(b));
}

// Async global->LDS DMA, 16 B per lane (out-proj A staging).
__device__ __forceinline__ void gll16(const unsigned short* g, unsigned short* l) {
    __builtin_amdgcn_global_load_lds(
        (const __attribute__((address_space(1))) unsigned int*)g,
        (__attribute__((address_space(3))) unsigned int*)l,
        16, 0, 0);
}

// ---------------------------------------------------------------------------
// Fused QKV projection, round 11: ONE block computes Q, K, Vt for its
// (m0, n0) tile — A (x, f32) staged ONCE (was 3x across z-blocks), three W
// panels reg-staged with fused f32->bf16, 24 MFMA per wave-iter (3x compute
// per sync event). TM=64, grid (128,4) = 512 = exactly 2 blocks/CU.
// Depth-1 two-buffer reg-staged pipeline (r10-verified hazard structure).
// Epilogues: verified LDS-bounce patterns (Q+rowscale, K, Vt-transpose).
// ---------------------------------------------------------------------------
__global__ __launch_bounds__(256, 2)
void qkv_fused(const float* __restrict__ x,
               const float* __restrict__ Wq, const float* __restrict__ bq, unsigned short* __restrict__ Qb,
               const float* __restrict__ Wk, const float* __restrict__ bk, unsigned short* __restrict__ Kb,
               const float* __restrict__ Wv, const float* __restrict__ bv, unsigned short* __restrict__ Vtb,
               const float* __restrict__ ent)
{
    constexpr int K   = EE;            // 512
    constexpr int N   = EE;            // 512
    constexpr int ASZ = 64 * 32;       // A-tile shorts
    constexpr int BSZ = 128 * 32;      // one W-panel shorts
    constexpr int BUF = ASZ + 3 * BSZ; // 14336
    __shared__ unsigned short lds[2 * BUF];   // 57344 B -> 2 blocks/CU

    const int tid  = threadIdx.x;
    const int wave = tid >> 6, lane = tid & 63;
    const int quad = lane >> 4, r16 = lane & 15;
    const int m0 = blockIdx.x * 64, n0 = blockIdx.y * 128;
    const int wm0 = (wave >> 1) * 32, wn0 = (wave & 1) * 64;

    const float* Ws[3] = {Wq, Wk, Wv};

    f32x4 acc[3][2][4];
    const f32x4 zero = {0.f, 0.f, 0.f, 0.f};
    #pragma unroll
    for (int o = 0; o < 3; ++o)
        #pragma unroll
        for (int mt = 0; mt < 2; ++mt)
            #pragma unroll
            for (int nt = 0; nt < 4; ++nt) acc[o][mt][nt] = zero;

    const int swz = (r16 >> 1) & 3;   // fragment-read chunk swizzle

    const int cbA = wave * 64, cA = cbA + lane;
    const int rowA = cA >> 2, ccA = (cA & 3) ^ ((rowA >> 1) & 3);
    int wcb[2], wrow[2], wcc[2];
    #pragma unroll
    for (int j = 0; j < 2; ++j) {
        const int cb = wave * 64 + j * 256, c = cb + lane;
        wcb[j] = cb; wrow[j] = c >> 2; wcc[j] = (c & 3) ^ ((wrow[j] >> 1) & 3);
    }

    f32x4 ra[2];        // held A f32 loads
    f32x4 rw[3][2][2];  // held W f32 loads [panel][chunk][half]

    auto issue = [&](int k0) {
        const float* pa = &x[(size_t)(m0 + rowA) * K + k0 + ccA * 8];
        ra[0] = *reinterpret_cast<const f32x4*>(pa);
        ra[1] = *reinterpret_cast<const f32x4*>(pa + 4);
        #pragma unroll
        for (int o = 0; o < 3; ++o)
            #pragma unroll
            for (int j = 0; j < 2; ++j) {
                const float* p = &Ws[o][(size_t)(n0 + wrow[j]) * K + k0 + wcc[j] * 8];
                rw[o][j][0] = *reinterpret_cast<const f32x4*>(p);
                rw[o][j][1] = *reinterpret_cast<const f32x4*>(p + 4);
            }
    };
    auto commit = [&](int bi) {
        unsigned short* As = lds + bi * BUF;
        const u32x4 va = {cvtpk(ra[0][0], ra[0][1]), cvtpk(ra[0][2], ra[0][3]),
                          cvtpk(ra[1][0], ra[1][1]), cvtpk(ra[1][2], ra[1][3])};
        *reinterpret_cast<u32x4*>(&As[(cbA + lane) * 8]) = va;
        #pragma unroll
        for (int o = 0; o < 3; ++o) {
            unsigned short* Bo = lds + bi * BUF + ASZ + o * BSZ;
            #pragma unroll
            for (int j = 0; j < 2; ++j) {
                const u32x4 v = {cvtpk(rw[o][j][0][0], rw[o][j][0][1]), cvtpk(rw[o][j][0][2], rw[o][j][0][3]),
                                 cvtpk(rw[o][j][1][0], rw[o][j][1][1]), cvtpk(rw[o][j][1][2], rw[o][j][1][3])};
                *reinterpret_cast<u32x4*>(&Bo[(wcb[j] + lane) * 8]) = v;
            }
        }
    };

    issue(0);
    asm volatile("s_waitcnt vmcnt(0)" ::: "memory");
    commit(0);
    issue(32);

    constexpr int NI = K / 32;   // 16
    for (int i = 0; i < NI; ++i) {
        const int cur = i & 1;
        asm volatile("s_waitcnt lgkmcnt(0)" ::: "memory");   // my ds_writes drained
        __builtin_amdgcn_s_barrier();
        __builtin_amdgcn_sched_barrier(0);
        if (i + 1 < NI) {
            asm volatile("s_waitcnt vmcnt(0)" ::: "memory"); // loads(i+1) landed
            commit(cur ^ 1);
        }
        if (i + 2 < NI) issue((i + 2) * 32);

        const unsigned short* As = lds + cur * BUF;
        bf16x8 af[2];
        #pragma unroll
        for (int t = 0; t < 2; ++t)
            af[t] = *reinterpret_cast<const bf16x8*>(
                &As[((wm0 + t * 16 + r16) * 4 + (quad ^ swz)) * 8]);
        #pragma unroll
        for (int o = 0; o < 3; ++o) {
            const unsigned short* Bo = lds + cur * BUF + ASZ + o * BSZ;
            bf16x8 bfr[4];
            #pragma unroll
            for (int t = 0; t < 4; ++t)
                bfr[t] = *reinterpret_cast<const bf16x8*>(
                    &Bo[((wn0 + t * 16 + r16) * 4 + (quad ^ swz)) * 8]);
            #pragma unroll
            for (int mt = 0; mt < 2; ++mt)
                #pragma unroll
                for (int nt = 0; nt < 4; ++nt)
                    acc[o][mt][nt] = __builtin_amdgcn_mfma_f32_16x16x32_bf16(
                        af[mt], bfr[nt], acc[o][mt][nt], 0, 0, 0);
        }
    }

    // ---- Epilogues (C/D layout: col = r16, row = quad*4 + reg; m89). ----
    // Q then K: straight bounce [row][col] stride 132 -> coalesced stores.
    #pragma unroll
    for (int o = 0; o < 2; ++o) {
        const float* bias = (o == 0) ? bq : bk;
        unsigned short* dst = (o == 0) ? Qb : Kb;
        __syncthreads();
        #pragma unroll
        for (int mt = 0; mt < 2; ++mt) {
            float rs[4];
            #pragma unroll
            for (int r = 0; r < 4; ++r) {
                const int grow = m0 + wm0 + mt * 16 + quad * 4 + r;
                rs[r] = (o == 0) ? ent[grow & (SS - 1)] * 0.18033688f : 1.0f;
            }
            #pragma unroll
            for (int nt = 0; nt < 4; ++nt) {
                const int col = wn0 + nt * 16 + r16;
                const float bvv = bias[n0 + col];
                #pragma unroll
                for (int r = 0; r < 4; ++r) {
                    const int row = wm0 + mt * 16 + quad * 4 + r;
                    lds[row * 132 + col] = f2bf((acc[o][mt][nt][r] + bvv) * rs[r]);
                }
            }
        }
        __syncthreads();
        const int scol = (tid & 15) * 8;
        #pragma unroll
        for (int p = 0; p < 4; ++p) {
            const int row = p * 16 + (tid >> 4);   // 0..63
            const uint2 lo = *reinterpret_cast<const uint2*>(&lds[row * 132 + scol]);
            const uint2 hi = *reinterpret_cast<const uint2*>(&lds[row * 132 + scol + 4]);
            const u32x4 v = {lo.x, lo.y, hi.x, hi.y};
            *reinterpret_cast<u32x4*>(&dst[(size_t)(m0 + row) * N + n0 + scol]) = v;
        }
    }
    // Vt: transpose bounce [d_local][s_local] stride 68 -> coalesced stores.
    __syncthreads();
    #pragma unroll
    for (int mt = 0; mt < 2; ++mt) {
        const int s_local = wm0 + mt * 16 + quad * 4;
        #pragma unroll
        for (int nt = 0; nt < 4; ++nt) {
            const int d_local = wn0 + nt * 16 + r16;
            const float bvv = bv[n0 + d_local];
            uint2 o2;
            o2.x = cvtpk(acc[2][mt][nt][0] + bvv, acc[2][mt][nt][1] + bvv);
            o2.y = cvtpk(acc[2][mt][nt][2] + bvv, acc[2][mt][nt][3] + bvv);
            *reinterpret_cast<uint2*>(&lds[d_local * 68 + s_local]) = o2;
        }
    }
    __syncthreads();
    const int bb = m0 >> 11, s0 = m0 & (SS - 1);
    unsigned short* Vtp = Vtb + (size_t)bb * EE * SS + s0;
    const int ocol = (tid & 7) * 8;
    #pragma unroll
    for (int p = 0; p < 4; ++p) {
        const int d = p * 32 + (tid >> 3);   // 0..127
        const uint2 lo = *reinterpret_cast<const uint2*>(&lds[d * 68 + ocol]);
        const uint2 hi = *reinterpret_cast<const uint2*>(&lds[d * 68 + ocol + 4]);
        const u32x4 v = {lo.x, lo.y, hi.x, hi.y};
        *reinterpret_cast<u32x4*>(&Vtp[(size_t)(n0 + d) * SS + ocol]) = v;
    }
}

// ---------------------------------------------------------------------------
// Out-proj GEMM (round-10 verified structure): C(f32) = A(bf16) @ W^T + b.
// A via gll16 DMA; W reg-staged f32->bf16; depth-2 3-buffer pipeline.
// ---------------------------------------------------------------------------
__global__ __launch_bounds__(256, 3)
void gemm_out(const unsigned short* __restrict__ Abf,
              const float* __restrict__ W, const float* __restrict__ bias,
              float* __restrict__ C, int M, int N, int K)
{
    constexpr int TM = 64;
    constexpr int STG = 3 * TM * 32;
    __shared__ unsigned short lds[STG + 3 * 128 * 32];
    unsigned short* As = lds;
    unsigned short* Bs = lds + STG;

    const int tid  = threadIdx.x;
    const int wave = tid >> 6, lane = tid & 63;
    const int quad = lane >> 4, r16 = lane & 15;
    const int m0 = blockIdx.x * TM, n0 = blockIdx.y * 128;
    const int wm0 = (wave >> 1) * (TM / 2), wn0 = (wave & 1) * 64;

    f32x4 acc[2][4];
    const f32x4 zero = {0.f, 0.f, 0.f, 0.f};
    #pragma unroll
    for (int i = 0; i < 2; ++i)
        #pragma unroll
        for (int j = 0; j < 4; ++j) acc[i][j] = zero;

    const int swz = (r16 >> 1) & 3;

    const int cbA = wave * 64, cA = cbA + lane;
    const int rowA = cA >> 2, ccA = (cA & 3) ^ ((rowA >> 1) & 3);
    int wcb[2], wrow[2], wcc[2];
    #pragma unroll
    for (int j = 0; j < 2; ++j) {
        const int cb = wave * 64 + j * 256, c = cb + lane;
        wcb[j] = cb; wrow[j] = c >> 2; wcc[j] = (c & 3) ^ ((wrow[j] >> 1) & 3);
    }
    f32x4 rw[4];

    auto issue = [&](int bi, int k0) {
        gll16(&Abf[(size_t)(m0 + rowA) * K + k0 + ccA * 8], &As[bi * TM * 32 + cbA * 8]);
        #pragma unroll
        for (int j = 0; j < 2; ++j) {
            const float* p = &W[(size_t)(n0 + wrow[j]) * K + k0 + wcc[j] * 8];
            rw[2 * j]     = *reinterpret_cast<const f32x4*>(p);
            rw[2 * j + 1] = *reinterpret_cast<const f32x4*>(p + 4);
        }
    };
    auto commit = [&](int bi) {
        #pragma unroll
        for (int j = 0; j < 2; ++j) {
            const u32x4 v = {cvtpk(rw[2*j][0], rw[2*j][1]), cvtpk(rw[2*j][2], rw[2*j][3]),
                             cvtpk(rw[2*j+1][0], rw[2*j+1][1]), cvtpk(rw[2*j+1][2], rw[2*j+1][3])};
            *reinterpret_cast<u32x4*>(&Bs[bi * 128 * 32 + (wcb[j] + lane) * 8]) = v;
        }
    };

    issue(0, 0);
    asm volatile("s_waitcnt vmcnt(0)" ::: "memory");
    commit(0);
    issue(1, 32);

    const int NI = K / 32;
    for (int i = 0; i < NI; ++i) {
        const int cur = i % 3;
        asm volatile("s_waitcnt lgkmcnt(0)" ::: "memory");
        __builtin_amdgcn_s_barrier();
        __builtin_amdgcn_sched_barrier(0);
        if (i + 1 < NI) {
            asm volatile("s_waitcnt vmcnt(0)" ::: "memory");
            commit((i + 1) % 3);
        }
        if (i + 2 < NI) issue((i + 2) % 3, (i + 2) * 32);

        bf16x8 af[2], bfr[4];
        #pragma unroll
        for (int t = 0; t < 2; ++t)
            af[t]  = *reinterpret_cast<bf16x8*>(&As[cur * TM * 32 + ((wm0 + t * 16 + r16) * 4 + (quad ^ swz)) * 8]);
        #pragma unroll
        for (int t = 0; t < 4; ++t)
            bfr[t] = *reinterpret_cast<bf16x8*>(&Bs[cur * 128 * 32 + ((wn0 + t * 16 + r16) * 4 + (quad ^ swz)) * 8]);
        #pragma unroll
        for (int mt = 0; mt < 2; ++mt)
            #pragma unroll
            for (int nt = 0; nt < 4; ++nt)
                acc[mt][nt] = __builtin_amdgcn_mfma_f32_16x16x32_bf16(
                    af[mt], bfr[nt], acc[mt][nt], 0, 0, 0);
    }

    float* fl = reinterpret_cast<float*>(lds);
    __syncthreads();
    #pragma unroll
    for (int mt = 0; mt < 2; ++mt) {
        #pragma unroll
        for (int nt = 0; nt < 4; ++nt) {
            const int col = wn0 + nt * 16 + r16;
            const float bvv = bias[n0 + col];
            #pragma unroll
            for (int r = 0; r < 4; ++r) {
                const int row = wm0 + mt * 16 + quad * 4 + r;
                fl[row * 132 + col] = acc[mt][nt][r] + bvv;
            }
        }
    }
    __syncthreads();
    const int scol = (tid & 31) * 4;
    #pragma unroll
    for (int p = 0; p < 8; ++p) {
        const int row = p * 8 + (tid >> 5);
        const f32x4 v = *reinterpret_cast<const f32x4*>(&fl[row * 132 + scol]);
        *reinterpret_cast<f32x4*>(&C[(size_t)(m0 + row) * N + n0 + scol]) = v;
    }
}

// ---------------------------------------------------------------------------
// MFMA flash attention — round-9 version VERBATIM (49.5 us, verified).
// ---------------------------------------------------------------------------
#define QBLK 128
#define KVB  128

__global__ __launch_bounds__(256, 2)
void attn_mfma(const unsigned short* __restrict__ Q,
               const unsigned short* __restrict__ K,
               const unsigned short* __restrict__ Vt,
               unsigned short* __restrict__ O)
{
    __shared__ unsigned short Ks[2][KVB * 64];   // [buf][k][64d]  16 KB each
    __shared__ unsigned short Vs[2][64 * KVB];   // [buf][d][128k] 16 KB each

    const int tid  = threadIdx.x;
    const int wave = tid >> 6, lane = tid & 63;
    const int quad = lane >> 4, r16 = lane & 15;
    const int h  = blockIdx.x;                   // h on blockIdx.x -> XCD = h
    const int q0 = blockIdx.y * QBLK;
    const int b  = blockIdx.z;
    const size_t base    = (size_t)b * SS * EE + (size_t)h * DD;   // Q/K/O rows
    const size_t base_vt = ((size_t)b * HH + h) * DD * SS;         // Vt rows

    bf16x8 qf[2][2];
    #pragma unroll
    for (int s = 0; s < 2; ++s) {
        const int qrow = q0 + s * 64 + wave * 16 + r16;
        #pragma unroll
        for (int dh = 0; dh < 2; ++dh)
            qf[s][dh] = *reinterpret_cast<const bf16x8*>(
                &Q[base + (size_t)qrow * EE + dh * 32 + quad * 8]);
    }

    const unsigned short* kp[4];
    const unsigned short* vp[4];
    int cbs[4];
    #pragma unroll
    for (int j = 0; j < 4; ++j) {
        const int cb = wave * 64 + j * 256;
        cbs[j] = cb;
        const int c  = cb + lane;
        const int rowK = c >> 3, ccK = (c & 7) ^ (rowK & 7);
        kp[j] = &K[base + (size_t)rowK * EE + ccK * 8];
        const int rowV = c >> 4, ccV = (c & 15) ^ (rowV & 15);
        vp[j] = &Vt[base_vt + (size_t)rowV * SS + ccV * 8];
    }

    auto stage = [&](int bi, int kt) {
        const size_t ko = (size_t)kt * KVB * EE;
        const int    vo = kt * KVB;
        #pragma unroll
        for (int j = 0; j < 4; ++j) {
            gll16(kp[j] + ko, &Ks[bi][cbs[j] * 8]);
            gll16(vp[j] + vo, &Vs[bi][cbs[j] * 8]);
        }
    };

    float l_lane[2] = {0.f, 0.f};
    f32x4 o_acc[2][4];
    const f32x4 zero = {0.f, 0.f, 0.f, 0.f};
    #pragma unroll
    for (int s = 0; s < 2; ++s)
        #pragma unroll
        for (int dt = 0; dt < 4; ++dt) o_acc[s][dt] = zero;

    const int swz7 = r16 & 7;

    stage(0, 0);

    constexpr int NT = SS / KVB;   // 16
    for (int kt = 0; kt < NT; ++kt) {
        const int cur = kt & 1;
        asm volatile("s_waitcnt vmcnt(0)" ::: "memory");
        __builtin_amdgcn_s_barrier();
        __builtin_amdgcn_sched_barrier(0);
        if (kt + 1 < NT) stage(cur ^ 1, kt + 1);

        const unsigned short* Kc = &Ks[cur][0];
        const unsigned short* Vc = &Vs[cur][0];

        f32x4 st[2][8];
        #pragma unroll
        for (int s = 0; s < 2; ++s)
            #pragma unroll
            for (int tn = 0; tn < 8; ++tn) st[s][tn] = zero;
        __builtin_amdgcn_s_setprio(1);
        #pragma unroll
        for (int tn = 0; tn < 8; ++tn) {
            const bf16x8 kf0 = *reinterpret_cast<const bf16x8*>(
                &Kc[((tn * 16 + r16) * 8 + (quad ^ swz7)) * 8]);
            const bf16x8 kf1 = *reinterpret_cast<const bf16x8*>(
                &Kc[((tn * 16 + r16) * 8 + ((quad + 4) ^ swz7)) * 8]);
            #pragma unroll
            for (int s = 0; s < 2; ++s) {
                st[s][tn] = __builtin_amdgcn_mfma_f32_16x16x32_bf16(kf0, qf[s][0], st[s][tn], 0, 0, 0);
                st[s][tn] = __builtin_amdgcn_mfma_f32_16x16x32_bf16(kf1, qf[s][1], st[s][tn], 0, 0, 0);
            }
        }
        __builtin_amdgcn_s_setprio(0);

        bf16x8 pf[2][4];
        #pragma unroll
        for (int s = 0; s < 2; ++s) {
            unsigned int w[8][2];
            #pragma unroll
            for (int tn = 0; tn < 8; ++tn) {
                const float p0 = ex2(st[s][tn][0]);
                const float p1 = ex2(st[s][tn][1]);
                const float p2 = ex2(st[s][tn][2]);
                const float p3 = ex2(st[s][tn][3]);
                l_lane[s] += (p0 + p1) + (p2 + p3);
                w[tn][0] = cvtpk(p0, p1);
                w[tn][1] = cvtpk(p2, p3);
            }
            #pragma unroll
            for (int j = 0; j < 4; ++j) {
                unsigned int a0 = w[2 * j][0], a2 = w[2 * j + 1][0];
                pl32(a0, a2); pl16(a0, a2);
                unsigned int a1 = w[2 * j][1], a3 = w[2 * j + 1][1];
                pl32(a1, a3); pl16(a1, a3);
                const u32x4 u = {a0, a1, a2, a3};
                pf[s][j] = __builtin_bit_cast(bf16x8, u);
            }
        }

        __builtin_amdgcn_s_setprio(1);
        #pragma unroll
        for (int j = 0; j < 4; ++j) {
            #pragma unroll
            for (int dt = 0; dt < 4; ++dt) {
                const bf16x8 vf = *reinterpret_cast<const bf16x8*>(
                    &Vc[((dt * 16 + r16) * 16 + ((4 * j + quad) ^ r16)) * 8]);
                o_acc[0][dt] = __builtin_amdgcn_mfma_f32_16x16x32_bf16(pf[0][j], vf, o_acc[0][dt], 0, 0, 0);
                o_acc[1][dt] = __builtin_amdgcn_mfma_f32_16x16x32_bf16(pf[1][j], vf, o_acc[1][dt], 0, 0, 0);
            }
        }
        __builtin_amdgcn_s_setprio(0);
    }

    float lq[2];
    #pragma unroll
    for (int s = 0; s < 2; ++s) {
        float l = l_lane[s];
        l += __shfl_xor(l, 16, 64);
        l += __shfl_xor(l, 32, 64);
        lq[s] = l;
    }

    unsigned short* ob = &Ks[0][0];
    __syncthreads();
    #pragma unroll
    for (int s = 0; s < 2; ++s) {
        #pragma unroll
        for (int r = 0; r < 4; ++r) {
            const float il = 1.0f / __shfl(lq[s], quad * 4 + r, 64);
            const int ql = s * 64 + wave * 16 + quad * 4 + r;
            #pragma unroll
            for (int dt = 0; dt < 4; ++dt)
                ob[ql * 68 + dt * 16 + r16] = f2bf(o_acc[s][dt][r] * il);
        }
    }
    __syncthreads();
    const int orow = tid >> 3, ocol = (tid & 7) * 8;
    #pragma unroll
    for (int p = 0; p < 4; ++p) {
        const int ql = p * 32 + orow;
        const uint2 lo = *reinterpret_cast<const uint2*>(&ob[ql * 68 + ocol]);
        const uint2 hi = *reinterpret_cast<const uint2*>(&ob[ql * 68 + ocol + 4]);
        const u32x4 v = {lo.x, lo.y, hi.x, hi.y};
        *reinterpret_cast<u32x4*>(&O[base + (size_t)(q0 + ql) * EE + ocol]) = v;
    }
}

extern "C" void kernel_launch(void* const* d_in, const int* in_sizes, int n_in,
                              void* d_out, int out_size, void* d_ws, size_t ws_size,
                              hipStream_t stream) {
    const float* x   = (const float*)d_in[0];
    const float* ent = (const float*)d_in[1];
    const float* Wq  = (const float*)d_in[2];
    const float* bq  = (const float*)d_in[3];
    const float* Wk  = (const float*)d_in[4];
    const float* bk  = (const float*)d_in[5];
    const float* Wv  = (const float*)d_in[6];
    const float* bv  = (const float*)d_in[7];
    const float* Wo  = (const float*)d_in[8];
    const float* bo  = (const float*)d_in[9];
    float* out = (float*)d_out;

    const size_t n_x = (size_t)BB * SS * EE;   // 4 Mi elements
    const size_t n_w = (size_t)EE * EE;

    unsigned short* xb  = (unsigned short*)d_ws;   // layout kept; xb..wob unused
    unsigned short* wqb = xb + n_x;
    unsigned short* wkb = wqb + n_w;
    unsigned short* wvb = wkb + n_w;
    unsigned short* wob = wvb + n_w;
    unsigned short* Qb  = wob + n_w;
    unsigned short* Kb  = Qb + n_x;
    unsigned short* Vtb = Kb + n_x;   // [b][h][d][s]
    unsigned short* AOb = Vtb + n_x;

    const int M = BB * SS;  // 8192

    // Fused QKV: one block per (m0,n0) computes Q, K, Vt (A staged once).
    dim3 gq(M / 64, EE / 128, 1);
    qkv_fused<<<gq, 256, 0, stream>>>(x, Wq, bq, Qb, Wk, bk, Kb, Wv, bv, Vtb, ent);

    // Grid (h, qtile, b): head -> XCD for K/V L2 residency; 2 blocks/CU.
    dim3 ga(HH, SS / QBLK, BB);
    attn_mfma<<<ga, 256, 0, stream>>>(Qb, Kb, Vtb, AOb);

    // Out-proj: A = AOb (bf16, gll16 DMA); W = Wo (f32, reg-staged).
    dim3 go(M / 64, EE / 128, 1);
    gemm_out<<<go, 256, 0, stream>>>(AOb, Wo, bo, out, M, EE, EE);
}

// Round 13
// 154.805 us; speedup vs baseline: 1.0278x; 1.0278x over previous
//
#include <hip/hip_runtime.h>
#include <hip/hip_bf16.h>

#define BB 4
#define SS 2048
#define EE 512
#define HH 8
#define DD 64

typedef __attribute__((ext_vector_type(8))) short bf16x8;   // 8 bf16 = 4 VGPRs
typedef __attribute__((ext_vector_type(4))) float f32x4;
typedef __attribute__((ext_vector_type(4))) unsigned int u32x4;

__device__ __forceinline__ unsigned short f2bf(float f) {
    __hip_bfloat16 h = __float2bfloat16(f);   // round-to-nearest
    return *reinterpret_cast<unsigned short*>(&h);
}

// HW packed f32->bf16 (RTNE). lo -> low 16, hi -> high 16 (T12 recipe).
__device__ __forceinline__ unsigned int cvtpk(float lo, float hi) {
    unsigned int r;
    asm("v_cvt_pk_bf16_f32 %0, %1, %2" : "=v"(r) : "v"(lo), "v"(hi));
    return r;
}

// Raw v_exp_f32 (2^x). Softmax wants flush-to-zero; |x| <~ 8 here.
__device__ __forceinline__ float ex2(float x) {
    float r;
    asm("v_exp_f32 %0, %1" : "=v"(r) : "v"(x));
    return r;
}

// gfx950 half-wave swaps (T12).
__device__ __forceinline__ void pl32(unsigned int& a, unsigned int& b) {
    asm("v_permlane32_swap_b32 %0, %1" : "+v"(a), "+v"(b));
}
__device__ __forceinline__ void pl16(unsigned int& a, unsigned int& b) {
    asm("v_permlane16_swap_b32 %0, %1" : "+v"(a), "+v"(b));
}

// Async global->LDS DMA, 16 B per lane. LDS dst = wave-uniform base + lane*16
// (m104/m108). Completion tracked by vmcnt.
__device__ __forceinline__ void gll16(const unsigned short* g, unsigned short* l) {
    __builtin_amdgcn_global_load_lds(
        (const __attribute__((address_space(1))) unsigned int*)g,
        (__attribute__((address_space(3))) unsigned int*)l,
        16, 0, 0);
}

// ---------------------------------------------------------------------------
// QKV GEMM with FUSED fp32->bf16 staging — r10 VERBATIM (passed, 156.2 us).
// C = A(f32 reg-staged)[M,K] @ W(f32 reg-staged)[N,K]^T + bias.
// Depth-2 3-buffer pipeline; LDS-bounced epilogues (Q/K straight, Vt transpose).
// ---------------------------------------------------------------------------
template<typename OutT, bool TRANSPOSE_V, int TM, bool AF32>
__global__ __launch_bounds__(256, 3)
void gemm_mfma_nt(const unsigned short* __restrict__ Abf,
                  const float* __restrict__ Af,
                  const float* __restrict__ W0, const float* __restrict__ b0, OutT* __restrict__ C0,
                  const float* __restrict__ W1, const float* __restrict__ b1, OutT* __restrict__ C1,
                  const float* __restrict__ W2, const float* __restrict__ b2, OutT* __restrict__ C2,
                  const float* __restrict__ rowscale,
                  int M, int N, int K)
{
    const float* W    = (blockIdx.z == 0) ? W0 : (blockIdx.z == 1) ? W1 : W2;
    const float* bias = (blockIdx.z == 0) ? b0 : (blockIdx.z == 1) ? b1 : b2;
    OutT* C           = (blockIdx.z == 0) ? C0 : (blockIdx.z == 1) ? C1 : C2;

    constexpr int MT  = TM / 32;            // m-tiles of 16 per wave (4 or 2)
    constexpr int NA  = TM / 64;            // A chunks per lane per stage
    constexpr int STG = 3 * TM * 32;        // A-staging shorts
    __shared__ unsigned short lds[STG + 3 * 128 * 32];
    unsigned short* As = lds;               // [3][TM*32]  chunk-swizzled
    unsigned short* Bs = lds + STG;         // [3][128*32] chunk-swizzled

    const int tid  = threadIdx.x;
    const int wave = tid >> 6, lane = tid & 63;
    const int quad = lane >> 4, r16 = lane & 15;
    const int m0 = blockIdx.x * TM, n0 = blockIdx.y * 128;
    const int wm0 = (wave >> 1) * (TM / 2), wn0 = (wave & 1) * 64;

    f32x4 acc[MT][4];
    const f32x4 zero = {0.f, 0.f, 0.f, 0.f};
    #pragma unroll
    for (int i = 0; i < MT; ++i)
        #pragma unroll
        for (int j = 0; j < 4; ++j) acc[i][j] = zero;

    const int swz = (r16 >> 1) & 3;   // fragment-read chunk swizzle

    int acb[NA > 0 ? NA : 1], arow[NA > 0 ? NA : 1], acc_[NA > 0 ? NA : 1];
    #pragma unroll
    for (int j = 0; j < NA; ++j) {
        const int cb = wave * 64 + j * 256, c = cb + lane;
        acb[j] = cb; arow[j] = c >> 2; acc_[j] = (c & 3) ^ ((arow[j] >> 1) & 3);
    }
    int wcb[2], wrow[2], wcc[2];
    #pragma unroll
    for (int j = 0; j < 2; ++j) {
        const int cb = wave * 64 + j * 256, c = cb + lane;
        wcb[j] = cb; wrow[j] = c >> 2; wcc[j] = (c & 3) ^ ((wrow[j] >> 1) & 3);
    }

    f32x4 ra[2 * (NA > 0 ? NA : 1)];   // held A f32 loads (AF32)
    f32x4 rw[4];                       // held W f32 loads

    auto issue = [&](int bi, int k0) {
        if constexpr (AF32) {
            #pragma unroll
            for (int j = 0; j < NA; ++j) {
                const float* p = &Af[(size_t)(m0 + arow[j]) * K + k0 + acc_[j] * 8];
                ra[2 * j]     = *reinterpret_cast<const f32x4*>(p);
                ra[2 * j + 1] = *reinterpret_cast<const f32x4*>(p + 4);
            }
        } else {
            #pragma unroll
            for (int j = 0; j < NA; ++j)
                gll16(&Abf[(size_t)(m0 + arow[j]) * K + k0 + acc_[j] * 8],
                      &As[bi * TM * 32 + acb[j] * 8]);
        }
        #pragma unroll
        for (int j = 0; j < 2; ++j) {
            const float* p = &W[(size_t)(n0 + wrow[j]) * K + k0 + wcc[j] * 8];
            rw[2 * j]     = *reinterpret_cast<const f32x4*>(p);
            rw[2 * j + 1] = *reinterpret_cast<const f32x4*>(p + 4);
        }
    };
    auto commit = [&](int bi) {
        if constexpr (AF32) {
            #pragma unroll
            for (int j = 0; j < NA; ++j) {
                const u32x4 v = {cvtpk(ra[2*j][0], ra[2*j][1]), cvtpk(ra[2*j][2], ra[2*j][3]),
                                 cvtpk(ra[2*j+1][0], ra[2*j+1][1]), cvtpk(ra[2*j+1][2], ra[2*j+1][3])};
                *reinterpret_cast<u32x4*>(&As[bi * TM * 32 + (acb[j] + lane) * 8]) = v;
            }
        }
        #pragma unroll
        for (int j = 0; j < 2; ++j) {
            const u32x4 v = {cvtpk(rw[2*j][0], rw[2*j][1]), cvtpk(rw[2*j][2], rw[2*j][3]),
                             cvtpk(rw[2*j+1][0], rw[2*j+1][1]), cvtpk(rw[2*j+1][2], rw[2*j+1][3])};
            *reinterpret_cast<u32x4*>(&Bs[bi * 128 * 32 + (wcb[j] + lane) * 8]) = v;
        }
    };

    issue(0, 0);
    asm volatile("s_waitcnt vmcnt(0)" ::: "memory");
    commit(0);
    issue(1, 32);

    const int NI = K / 32;
    for (int i = 0; i < NI; ++i) {
        const int cur = i % 3;
        asm volatile("s_waitcnt lgkmcnt(0)" ::: "memory");   // my ds_writes drained
        __builtin_amdgcn_s_barrier();
        __builtin_amdgcn_sched_barrier(0);
        if (i + 1 < NI) {
            asm volatile("s_waitcnt vmcnt(0)" ::: "memory"); // loads(i+1) landed
            commit((i + 1) % 3);
        }
        if (i + 2 < NI) issue((i + 2) % 3, (i + 2) * 32);

        bf16x8 af[MT], bfr[4];
        #pragma unroll
        for (int t = 0; t < MT; ++t)
            af[t]  = *reinterpret_cast<bf16x8*>(&As[cur * TM * 32 + ((wm0 + t * 16 + r16) * 4 + (quad ^ swz)) * 8]);
        #pragma unroll
        for (int t = 0; t < 4; ++t)
            bfr[t] = *reinterpret_cast<bf16x8*>(&Bs[cur * 128 * 32 + ((wn0 + t * 16 + r16) * 4 + (quad ^ swz)) * 8]);
        #pragma unroll
        for (int mt = 0; mt < MT; ++mt)
            #pragma unroll
            for (int nt = 0; nt < 4; ++nt)
                acc[mt][nt] = __builtin_amdgcn_mfma_f32_16x16x32_bf16(
                    af[mt], bfr[nt], acc[mt][nt], 0, 0, 0);
    }

    // Epilogue. C/D layout: col = lane&15, row = quad*4 + reg (m89-verified).
    if (TRANSPOSE_V && blockIdx.z == 2) {
        __syncthreads();
        #pragma unroll
        for (int mt = 0; mt < MT; ++mt) {
            const int s_local = wm0 + mt * 16 + quad * 4;   // 4 consecutive s
            #pragma unroll
            for (int nt = 0; nt < 4; ++nt) {
                const int d_local = wn0 + nt * 16 + r16;
                const float bv = bias[n0 + d_local];
                uint2 o;
                o.x = cvtpk(acc[mt][nt][0] + bv, acc[mt][nt][1] + bv);
                o.y = cvtpk(acc[mt][nt][2] + bv, acc[mt][nt][3] + bv);
                *reinterpret_cast<uint2*>(&lds[d_local * 132 + s_local]) = o;
            }
        }
        __syncthreads();
        const int bb = m0 >> 11, s0 = m0 & (SS - 1);
        unsigned short* Vtp = (unsigned short*)C2 + (size_t)bb * EE * SS + s0;
        const int scol = (tid & 15) * 8;
        #pragma unroll
        for (int p = 0; p < 8; ++p) {
            const int row = p * 16 + (tid >> 4);   // d_local 0..127
            const uint2 lo = *reinterpret_cast<const uint2*>(&lds[row * 132 + scol]);
            const uint2 hi = *reinterpret_cast<const uint2*>(&lds[row * 132 + scol + 4]);
            const u32x4 v = {lo.x, lo.y, hi.x, hi.y};
            *reinterpret_cast<u32x4*>(&Vtp[(size_t)(n0 + row) * SS + scol]) = v;
        }
        return;
    }
    if constexpr (sizeof(OutT) == 2) {
        const bool doscale = (rowscale != nullptr) && (blockIdx.z == 0);
        __syncthreads();
        #pragma unroll
        for (int mt = 0; mt < MT; ++mt) {
            float rs[4];
            #pragma unroll
            for (int r = 0; r < 4; ++r) {
                const int row = m0 + wm0 + mt * 16 + quad * 4 + r;
                rs[r] = doscale ? rowscale[row & (SS - 1)] * 0.18033688f : 1.0f;
            }
            #pragma unroll
            for (int nt = 0; nt < 4; ++nt) {
                const int col = wn0 + nt * 16 + r16;
                const float bv = bias[n0 + col];
                #pragma unroll
                for (int r = 0; r < 4; ++r) {
                    const int row = wm0 + mt * 16 + quad * 4 + r;
                    lds[row * 132 + col] = f2bf((acc[mt][nt][r] + bv) * rs[r]);
                }
            }
        }
        __syncthreads();
        const int scol = (tid & 15) * 8;
        #pragma unroll
        for (int p = 0; p < TM / 16; ++p) {
            const int row = p * 16 + (tid >> 4);   // 0..TM-1
            const uint2 lo = *reinterpret_cast<const uint2*>(&lds[row * 132 + scol]);
            const uint2 hi = *reinterpret_cast<const uint2*>(&lds[row * 132 + scol + 4]);
            const u32x4 v = {lo.x, lo.y, hi.x, hi.y};
            *reinterpret_cast<u32x4*>(&((unsigned short*)C)[(size_t)(m0 + row) * N + n0 + scol]) = v;
        }
    } else {
        float* fl = reinterpret_cast<float*>(lds);   // [TM][132] f32 tile
        __syncthreads();
        #pragma unroll
        for (int mt = 0; mt < MT; ++mt) {
            #pragma unroll
            for (int nt = 0; nt < 4; ++nt) {
                const int col = wn0 + nt * 16 + r16;
                const float bv = bias[n0 + col];
                #pragma unroll
                for (int r = 0; r < 4; ++r) {
                    const int row = wm0 + mt * 16 + quad * 4 + r;
                    fl[row * 132 + col] = acc[mt][nt][r] + bv;
                }
            }
        }
        __syncthreads();
        const int scol = (tid & 31) * 4;
        #pragma unroll
        for (int p = 0; p < TM / 8; ++p) {
            const int row = p * 8 + (tid >> 5);
            const f32x4 v = *reinterpret_cast<const f32x4*>(&fl[row * 132 + scol]);
            *reinterpret_cast<f32x4*>(&((float*)C)[(size_t)(m0 + row) * N + n0 + scol]) = v;
        }
    }
}

// ---------------------------------------------------------------------------
// Out-proj GEMM, round 13: BK=64 — half the barriers (r9's proven lever).
// Each 64-wide K-tile is stored as TWO verbatim 32-wide sub-tiles (identical
// chunk-swizzled layout, staging geometry, and fragment addressing as r10);
// the loop consumes both between one barrier pair. 8 iters instead of 16.
// Depth-2 3-buffer pipeline unchanged. LDS 72 KB -> 2 blocks/CU (grid 512 =
// exactly 2/CU, no tail).
// ---------------------------------------------------------------------------
__global__ __launch_bounds__(256, 2)
void gemm_out_bk64(const unsigned short* __restrict__ Abf,
                   const float* __restrict__ W, const float* __restrict__ bias,
                   float* __restrict__ C, int M, int N, int K)
{
    constexpr int TM  = 64;
    constexpr int ASB = TM * 32;    // 2048 shorts per A sub-tile
    constexpr int BSB = 128 * 32;   // 4096 shorts per B sub-tile
    // [3 bufs][2 subs]: A then B regions.
    __shared__ unsigned short lds[3 * 2 * ASB + 3 * 2 * BSB];   // 73728 B
    unsigned short* As = lds;                    // (bi*2+s)*ASB
    unsigned short* Bs = lds + 3 * 2 * ASB;      // (bi*2+s)*BSB

    const int tid  = threadIdx.x;
    const int wave = tid >> 6, lane = tid & 63;
    const int quad = lane >> 4, r16 = lane & 15;
    const int m0 = blockIdx.x * TM, n0 = blockIdx.y * 128;
    const int wm0 = (wave >> 1) * 32, wn0 = (wave & 1) * 64;

    f32x4 acc[2][4];
    const f32x4 zero = {0.f, 0.f, 0.f, 0.f};
    #pragma unroll
    for (int i = 0; i < 2; ++i)
        #pragma unroll
        for (int j = 0; j < 4; ++j) acc[i][j] = zero;

    const int swz = (r16 >> 1) & 3;

    // Per-32-wide-sub staging geometry — bit-identical to r10.
    const int cbA = wave * 64, cA = cbA + lane;
    const int rowA = cA >> 2, ccA = (cA & 3) ^ ((rowA >> 1) & 3);
    int wcb[2], wrow[2], wcc[2];
    #pragma unroll
    for (int j = 0; j < 2; ++j) {
        const int cb = wave * 64 + j * 256, c = cb + lane;
        wcb[j] = cb; wrow[j] = c >> 2; wcc[j] = (c & 3) ^ ((wrow[j] >> 1) & 3);
    }
    f32x4 rw[2][2][2];   // [sub][chunk][half] held W f32 loads (static idx)

    auto issue = [&](int bi, int k0) {
        #pragma unroll
        for (int s = 0; s < 2; ++s) {
            const int ks = k0 + s * 32;
            gll16(&Abf[(size_t)(m0 + rowA) * K + ks + ccA * 8],
                  &As[(bi * 2 + s) * ASB + cbA * 8]);
            #pragma unroll
            for (int j = 0; j < 2; ++j) {
                const float* p = &W[(size_t)(n0 + wrow[j]) * K + ks + wcc[j] * 8];
                rw[s][j][0] = *reinterpret_cast<const f32x4*>(p);
                rw[s][j][1] = *reinterpret_cast<const f32x4*>(p + 4);
            }
        }
    };
    auto commit = [&](int bi) {
        #pragma unroll
        for (int s = 0; s < 2; ++s)
            #pragma unroll
            for (int j = 0; j < 2; ++j) {
                const u32x4 v = {cvtpk(rw[s][j][0][0], rw[s][j][0][1]), cvtpk(rw[s][j][0][2], rw[s][j][0][3]),
                                 cvtpk(rw[s][j][1][0], rw[s][j][1][1]), cvtpk(rw[s][j][1][2], rw[s][j][1][3])};
                *reinterpret_cast<u32x4*>(&Bs[(bi * 2 + s) * BSB + (wcb[j] + lane) * 8]) = v;
            }
    };

    issue(0, 0);
    asm volatile("s_waitcnt vmcnt(0)" ::: "memory");
    commit(0);
    issue(1, 64);

    const int NI = K / 64;   // 8
    for (int i = 0; i < NI; ++i) {
        const int cur = i % 3;
        asm volatile("s_waitcnt lgkmcnt(0)" ::: "memory");   // my ds_writes drained
        __builtin_amdgcn_s_barrier();
        __builtin_amdgcn_sched_barrier(0);
        if (i + 1 < NI) {
            asm volatile("s_waitcnt vmcnt(0)" ::: "memory"); // loads(i+1) landed
            commit((i + 1) % 3);
        }
        if (i + 2 < NI) issue((i + 2) % 3, (i + 2) * 64);

        #pragma unroll
        for (int s = 0; s < 2; ++s) {
            const unsigned short* Asub = &As[(cur * 2 + s) * ASB];
            const unsigned short* Bsub = &Bs[(cur * 2 + s) * BSB];
            bf16x8 af[2], bfr[4];
            #pragma unroll
            for (int t = 0; t < 2; ++t)
                af[t]  = *reinterpret_cast<const bf16x8*>(&Asub[((wm0 + t * 16 + r16) * 4 + (quad ^ swz)) * 8]);
            #pragma unroll
            for (int t = 0; t < 4; ++t)
                bfr[t] = *reinterpret_cast<const bf16x8*>(&Bsub[((wn0 + t * 16 + r16) * 4 + (quad ^ swz)) * 8]);
            #pragma unroll
            for (int mt = 0; mt < 2; ++mt)
                #pragma unroll
                for (int nt = 0; nt < 4; ++nt)
                    acc[mt][nt] = __builtin_amdgcn_mfma_f32_16x16x32_bf16(
                        af[mt], bfr[nt], acc[mt][nt], 0, 0, 0);
        }
    }

    // fp32 epilogue: LDS bounce -> coalesced f32x4 stores (r9/r10 verified).
    float* fl = reinterpret_cast<float*>(lds);   // [64][132] f32 tile
    __syncthreads();
    #pragma unroll
    for (int mt = 0; mt < 2; ++mt) {
        #pragma unroll
        for (int nt = 0; nt < 4; ++nt) {
            const int col = wn0 + nt * 16 + r16;
            const float bvv = bias[n0 + col];
            #pragma unroll
            for (int r = 0; r < 4; ++r) {
                const int row = wm0 + mt * 16 + quad * 4 + r;
                fl[row * 132 + col] = acc[mt][nt][r] + bvv;
            }
        }
    }
    __syncthreads();
    const int scol = (tid & 31) * 4;
    #pragma unroll
    for (int p = 0; p < 8; ++p) {
        const int row = p * 8 + (tid >> 5);
        const f32x4 v = *reinterpret_cast<const f32x4*>(&fl[row * 132 + scol]);
        *reinterpret_cast<f32x4*>(&C[(size_t)(m0 + row) * N + n0 + scol]) = v;
    }
}

// ---------------------------------------------------------------------------
// MFMA flash attention — round-9 version VERBATIM (49.5 us, verified).
// KVBLK=128, QBLK=128, depth-1 stage-ahead, 2 blocks/CU, v_exp, setprio,
// in-register P via cvt_pk + permlane, O LDS-bounce epilogue.
// ---------------------------------------------------------------------------
#define QBLK 128
#define KVB  128

__global__ __launch_bounds__(256, 2)
void attn_mfma(const unsigned short* __restrict__ Q,
               const unsigned short* __restrict__ K,
               const unsigned short* __restrict__ Vt,
               unsigned short* __restrict__ O)
{
    __shared__ unsigned short Ks[2][KVB * 64];   // [buf][k][64d]  16 KB each
    __shared__ unsigned short Vs[2][64 * KVB];   // [buf][d][128k] 16 KB each

    const int tid  = threadIdx.x;
    const int wave = tid >> 6, lane = tid & 63;
    const int quad = lane >> 4, r16 = lane & 15;
    const int h  = blockIdx.x;                   // h on blockIdx.x -> XCD = h
    const int q0 = blockIdx.y * QBLK;
    const int b  = blockIdx.z;
    const size_t base    = (size_t)b * SS * EE + (size_t)h * DD;   // Q/K/O rows
    const size_t base_vt = ((size_t)b * HH + h) * DD * SS;         // Vt rows

    bf16x8 qf[2][2];
    #pragma unroll
    for (int s = 0; s < 2; ++s) {
        const int qrow = q0 + s * 64 + wave * 16 + r16;
        #pragma unroll
        for (int dh = 0; dh < 2; ++dh)
            qf[s][dh] = *reinterpret_cast<const bf16x8*>(
                &Q[base + (size_t)qrow * EE + dh * 32 + quad * 8]);
    }

    const unsigned short* kp[4];
    const unsigned short* vp[4];
    int cbs[4];
    #pragma unroll
    for (int j = 0; j < 4; ++j) {
        const int cb = wave * 64 + j * 256;
        cbs[j] = cb;
        const int c  = cb + lane;
        const int rowK = c >> 3, ccK = (c & 7) ^ (rowK & 7);
        kp[j] = &K[base + (size_t)rowK * EE + ccK * 8];
        const int rowV = c >> 4, ccV = (c & 15) ^ (rowV & 15);
        vp[j] = &Vt[base_vt + (size_t)rowV * SS + ccV * 8];
    }

    auto stage = [&](int bi, int kt) {
        const size_t ko = (size_t)kt * KVB * EE;
        const int    vo = kt * KVB;
        #pragma unroll
        for (int j = 0; j < 4; ++j) {
            gll16(kp[j] + ko, &Ks[bi][cbs[j] * 8]);
            gll16(vp[j] + vo, &Vs[bi][cbs[j] * 8]);
        }
    };

    float l_lane[2] = {0.f, 0.f};
    f32x4 o_acc[2][4];
    const f32x4 zero = {0.f, 0.f, 0.f, 0.f};
    #pragma unroll
    for (int s = 0; s < 2; ++s)
        #pragma unroll
        for (int dt = 0; dt < 4; ++dt) o_acc[s][dt] = zero;

    const int swz7 = r16 & 7;

    stage(0, 0);

    constexpr int NT = SS / KVB;   // 16
    for (int kt = 0; kt < NT; ++kt) {
        const int cur = kt & 1;
        asm volatile("s_waitcnt vmcnt(0)" ::: "memory");
        __builtin_amdgcn_s_barrier();
        __builtin_amdgcn_sched_barrier(0);
        if (kt + 1 < NT) stage(cur ^ 1, kt + 1);

        const unsigned short* Kc = &Ks[cur][0];
        const unsigned short* Vc = &Vs[cur][0];

        f32x4 st[2][8];
        #pragma unroll
        for (int s = 0; s < 2; ++s)
            #pragma unroll
            for (int tn = 0; tn < 8; ++tn) st[s][tn] = zero;
        __builtin_amdgcn_s_setprio(1);
        #pragma unroll
        for (int tn = 0; tn < 8; ++tn) {
            const bf16x8 kf0 = *reinterpret_cast<const bf16x8*>(
                &Kc[((tn * 16 + r16) * 8 + (quad ^ swz7)) * 8]);
            const bf16x8 kf1 = *reinterpret_cast<const bf16x8*>(
                &Kc[((tn * 16 + r16) * 8 + ((quad + 4) ^ swz7)) * 8]);
            #pragma unroll
            for (int s = 0; s < 2; ++s) {
                st[s][tn] = __builtin_amdgcn_mfma_f32_16x16x32_bf16(kf0, qf[s][0], st[s][tn], 0, 0, 0);
                st[s][tn] = __builtin_amdgcn_mfma_f32_16x16x32_bf16(kf1, qf[s][1], st[s][tn], 0, 0, 0);
            }
        }
        __builtin_amdgcn_s_setprio(0);

        bf16x8 pf[2][4];
        #pragma unroll
        for (int s = 0; s < 2; ++s) {
            unsigned int w[8][2];
            #pragma unroll
            for (int tn = 0; tn < 8; ++tn) {
                const float p0 = ex2(st[s][tn][0]);
                const float p1 = ex2(st[s][tn][1]);
                const float p2 = ex2(st[s][tn][2]);
                const float p3 = ex2(st[s][tn][3]);
                l_lane[s] += (p0 + p1) + (p2 + p3);
                w[tn][0] = cvtpk(p0, p1);
                w[tn][1] = cvtpk(p2, p3);
            }
            #pragma unroll
            for (int j = 0; j < 4; ++j) {
                unsigned int a0 = w[2 * j][0], a2 = w[2 * j + 1][0];
                pl32(a0, a2); pl16(a0, a2);
                unsigned int a1 = w[2 * j][1], a3 = w[2 * j + 1][1];
                pl32(a1, a3); pl16(a1, a3);
                const u32x4 u = {a0, a1, a2, a3};
                pf[s][j] = __builtin_bit_cast(bf16x8, u);
            }
        }

        __builtin_amdgcn_s_setprio(1);
        #pragma unroll
        for (int j = 0; j < 4; ++j) {
            #pragma unroll
            for (int dt = 0; dt < 4; ++dt) {
                const bf16x8 vf = *reinterpret_cast<const bf16x8*>(
                    &Vc[((dt * 16 + r16) * 16 + ((4 * j + quad) ^ r16)) * 8]);
                o_acc[0][dt] = __builtin_amdgcn_mfma_f32_16x16x32_bf16(pf[0][j], vf, o_acc[0][dt], 0, 0, 0);
                o_acc[1][dt] = __builtin_amdgcn_mfma_f32_16x16x32_bf16(pf[1][j], vf, o_acc[1][dt], 0, 0, 0);
            }
        }
        __builtin_amdgcn_s_setprio(0);
    }

    float lq[2];
    #pragma unroll
    for (int s = 0; s < 2; ++s) {
        float l = l_lane[s];
        l += __shfl_xor(l, 16, 64);
        l += __shfl_xor(l, 32, 64);
        lq[s] = l;
    }

    unsigned short* ob = &Ks[0][0];
    __syncthreads();
    #pragma unroll
    for (int s = 0; s < 2; ++s) {
        #pragma unroll
        for (int r = 0; r < 4; ++r) {
            const float il = 1.0f / __shfl(lq[s], quad * 4 + r, 64);
            const int ql = s * 64 + wave * 16 + quad * 4 + r;
            #pragma unroll
            for (int dt = 0; dt < 4; ++dt)
                ob[ql * 68 + dt * 16 + r16] = f2bf(o_acc[s][dt][r] * il);
        }
    }
    __syncthreads();
    const int orow = tid >> 3, ocol = (tid & 7) * 8;
    #pragma unroll
    for (int p = 0; p < 4; ++p) {
        const int ql = p * 32 + orow;
        const uint2 lo = *reinterpret_cast<const uint2*>(&ob[ql * 68 + ocol]);
        const uint2 hi = *reinterpret_cast<const uint2*>(&ob[ql * 68 + ocol + 4]);
        const u32x4 v = {lo.x, lo.y, hi.x, hi.y};
        *reinterpret_cast<u32x4*>(&O[base + (size_t)(q0 + ql) * EE + ocol]) = v;
    }
}

extern "C" void kernel_launch(void* const* d_in, const int* in_sizes, int n_in,
                              void* d_out, int out_size, void* d_ws, size_t ws_size,
                              hipStream_t stream) {
    const float* x   = (const float*)d_in[0];
    const float* ent = (const float*)d_in[1];
    const float* Wq  = (const float*)d_in[2];
    const float* bq  = (const float*)d_in[3];
    const float* Wk  = (const float*)d_in[4];
    const float* bk  = (const float*)d_in[5];
    const float* Wv  = (const float*)d_in[6];
    const float* bv  = (const float*)d_in[7];
    const float* Wo  = (const float*)d_in[8];
    const float* bo  = (const float*)d_in[9];
    float* out = (float*)d_out;

    const size_t n_x = (size_t)BB * SS * EE;   // 4 Mi elements
    const size_t n_w = (size_t)EE * EE;

    unsigned short* xb  = (unsigned short*)d_ws;   // layout kept; xb..wob unused
    unsigned short* wqb = xb + n_x;
    unsigned short* wkb = wqb + n_w;
    unsigned short* wvb = wkb + n_w;
    unsigned short* wob = wvb + n_w;
    unsigned short* Qb  = wob + n_w;
    unsigned short* Kb  = Qb + n_x;
    unsigned short* Vtb = Kb + n_x;   // [b][h][d][s]
    unsigned short* AOb = Vtb + n_x;

    const int M = BB * SS;  // 8192

    // Fused QKV projection (r10 verbatim); Q pre-scaled by ent*0.125*log2e.
    dim3 gq(M / 128, EE / 128, 3);
    gemm_mfma_nt<unsigned short, true, 128, true><<<gq, 256, 0, stream>>>(
        nullptr, x, Wq, bq, Qb, Wk, bk, Kb, Wv, bv, Vtb, ent, M, EE, EE);

    // Grid (h, qtile, b): head -> XCD for K/V L2 residency; 2 blocks/CU.
    dim3 ga(HH, SS / QBLK, BB);
    attn_mfma<<<ga, 256, 0, stream>>>(Qb, Kb, Vtb, AOb);

    // Out-proj: BK=64 (half the barriers), A via gll16 DMA, W f32-reg-staged.
    dim3 go(M / 64, EE / 128, 1);
    gemm_out_bk64<<<go, 256, 0, stream>>>(AOb, Wo, bo, out, M, EE, EE);
}